// Round 1
// baseline (3731.565 us; speedup 1.0000x reference)
//
#include <hip/hip_runtime.h>

// HRMHead: B=1024, T=512, F=128, HH=HL=64, HIGH_PERIOD=10
// ws layout (floats):
//   lWih_t [192][192] @ 0      : lWih_t[k][o] = low_Wih[o][k]   (k<128: x-part, k>=128: h_high-part)
//   lWhh_t [ 64][192] @ 36864  : lWhh_t[k][o] = low_Whh[o][k]
//   hWih_t [128][192] @ 49152  : hWih_t[k][o] = high_Wih[o][k]
//   hWhh_t [ 64][192] @ 73728  : hWhh_t[k][o] = high_Whh[o][k]

#define NB 4

__device__ __forceinline__ float sigm(float v) { return 1.0f / (1.0f + __expf(-v)); }
__device__ __forceinline__ float tanh_fast(float v) { return 1.0f - 2.0f / (__expf(2.0f * v) + 1.0f); }

__global__ void prep_weights(const float* __restrict__ hWih, const float* __restrict__ hWhh,
                             const float* __restrict__ lWih, const float* __restrict__ lWhh,
                             float* __restrict__ ws) {
    int i = blockIdx.x * blockDim.x + threadIdx.x;
    float* lWih_t = ws;              // [192][192]
    float* lWhh_t = ws + 36864;      // [64][192]
    float* hWih_t = ws + 49152;      // [128][192]
    float* hWhh_t = ws + 73728;      // [64][192]
    if (i < 36864) { int o = i % 192, k = i / 192; lWih_t[k * 192 + o] = lWih[o * 192 + k]; }
    if (i < 12288) { int o = i % 192, k = i / 192; lWhh_t[k * 192 + o] = lWhh[o * 64 + k]; }
    if (i < 24576) { int o = i % 192, k = i / 192; hWih_t[k * 192 + o] = hWih[o * 128 + k]; }
    if (i < 12288) { int o = i % 192, k = i / 192; hWhh_t[k * 192 + o] = hWhh[o * 64 + k]; }
}

__global__ __launch_bounds__(256, 1)
void hrm_main(const float* __restrict__ x,
              const float* __restrict__ high_bih, const float* __restrict__ high_bhh,
              const float* __restrict__ low_bih,  const float* __restrict__ low_bhh,
              const float* __restrict__ head_W1,  const float* __restrict__ head_b1,
              const float* __restrict__ head_W2,  const float* __restrict__ head_b2,
              const float* __restrict__ ws, float* __restrict__ out) {
    const float* lWih_t = ws;
    const float* lWhh_t = ws + 36864;
    const float* hWih_t = ws + 49152;
    const float* hWhh_t = ws + 73728;

    __shared__ float xs[NB][128];
    __shared__ float hh[NB][64];
    __shared__ float hl[NB][64];
    __shared__ float ht0[NB][64], ht1[NB][64], ht2[NB][64];  // cached h_high @ lWih_h + low_bih

    const int tid = threadIdx.x;
    const int b   = tid >> 6;   // wave id = local row
    const int j   = tid & 63;   // lane = hidden index
    const int row = blockIdx.x * NB + b;

    hh[b][j] = 0.0f;
    hl[b][j] = 0.0f;
    __syncthreads();

    const float hbi0 = high_bih[j], hbi1 = high_bih[64 + j], hbi2 = high_bih[128 + j];
    const float hbh0 = high_bhh[j], hbh1 = high_bhh[64 + j], hbh2 = high_bhh[128 + j];
    const float lbi0 = low_bih[j],  lbi1 = low_bih[64 + j],  lbi2 = low_bih[128 + j];
    const float lbh0 = low_bhh[j],  lbh1 = low_bhh[64 + j],  lbh2 = low_bhh[128 + j];

    const float* xrow = x + (size_t)row * (512 * 128);

    for (int t = 0; t < 512; ++t) {
        // stage x_t for my row (coalesced: 64 lanes x float2 = 512B)
        float2 xv = *(const float2*)(xrow + t * 128 + 2 * j);
        xs[b][2 * j]     = xv.x;
        xs[b][2 * j + 1] = xv.y;
        __syncthreads();

        if (t % 10 == 0) {
            // ---- high GRU cell ----
            float gi0 = hbi0, gi1 = hbi1, gi2 = hbi2;
            {
                const float* w0 = hWih_t + j;
                const float* w1 = hWih_t + 64 + j;
                const float* w2 = hWih_t + 128 + j;
                #pragma unroll 8
                for (int k = 0; k < 128; ++k) {
                    float xk = xs[b][k];
                    gi0 = fmaf(xk, w0[k * 192], gi0);
                    gi1 = fmaf(xk, w1[k * 192], gi1);
                    gi2 = fmaf(xk, w2[k * 192], gi2);
                }
            }
            float gh0 = hbh0, gh1 = hbh1, gh2 = hbh2;
            {
                const float* v0 = hWhh_t + j;
                const float* v1 = hWhh_t + 64 + j;
                const float* v2 = hWhh_t + 128 + j;
                #pragma unroll 8
                for (int k = 0; k < 64; ++k) {
                    float hk = hh[b][k];
                    gh0 = fmaf(hk, v0[k * 192], gh0);
                    gh1 = fmaf(hk, v1[k * 192], gh1);
                    gh2 = fmaf(hk, v2[k * 192], gh2);
                }
            }
            float r = sigm(gi0 + gh0);
            float z = sigm(gi1 + gh1);
            float n = tanh_fast(gi2 + r * gh2);
            float hnew = (1.0f - z) * n + z * hh[b][j];
            __syncthreads();
            hh[b][j] = hnew;
            __syncthreads();

            // ---- recompute cached low gi h_high-part (+ low_bih) ----
            float t0 = lbi0, t1 = lbi1, t2 = lbi2;
            {
                const float* u0 = lWih_t + 128 * 192 + j;
                const float* u1 = lWih_t + 128 * 192 + 64 + j;
                const float* u2 = lWih_t + 128 * 192 + 128 + j;
                #pragma unroll 8
                for (int k = 0; k < 64; ++k) {
                    float hk = hh[b][k];
                    t0 = fmaf(hk, u0[k * 192], t0);
                    t1 = fmaf(hk, u1[k * 192], t1);
                    t2 = fmaf(hk, u2[k * 192], t2);
                }
            }
            ht0[b][j] = t0; ht1[b][j] = t1; ht2[b][j] = t2;
            __syncthreads();
        }

        // ---- low GRU cell ----
        float gi0 = ht0[b][j], gi1 = ht1[b][j], gi2 = ht2[b][j];
        {
            const float* w0 = lWih_t + j;
            const float* w1 = lWih_t + 64 + j;
            const float* w2 = lWih_t + 128 + j;
            #pragma unroll 8
            for (int k = 0; k < 128; ++k) {
                float xk = xs[b][k];
                gi0 = fmaf(xk, w0[k * 192], gi0);
                gi1 = fmaf(xk, w1[k * 192], gi1);
                gi2 = fmaf(xk, w2[k * 192], gi2);
            }
        }
        float gh0 = lbh0, gh1 = lbh1, gh2 = lbh2;
        {
            const float* v0 = lWhh_t + j;
            const float* v1 = lWhh_t + 64 + j;
            const float* v2 = lWhh_t + 128 + j;
            #pragma unroll 8
            for (int k = 0; k < 64; ++k) {
                float hk = hl[b][k];
                gh0 = fmaf(hk, v0[k * 192], gh0);
                gh1 = fmaf(hk, v1[k * 192], gh1);
                gh2 = fmaf(hk, v2[k * 192], gh2);
            }
        }
        float r = sigm(gi0 + gh0);
        float z = sigm(gi1 + gh1);
        float n = tanh_fast(gi2 + r * gh2);
        float hnew = (1.0f - z) * n + z * hl[b][j];
        __syncthreads();
        hl[b][j] = hnew;
        __syncthreads();
    }

    // ---- head: relu(h_low @ W1.T + b1) @ W2.T + b2 -> sigmoid ----
    float hd = head_b1[j];
    #pragma unroll 8
    for (int k = 0; k < 64; ++k) hd = fmaf(hl[b][k], head_W1[j * 64 + k], hd);
    hd = fmaxf(hd, 0.0f);
    float v = hd * head_W2[j];
    #pragma unroll
    for (int off = 32; off > 0; off >>= 1) v += __shfl_down(v, off);
    if (j == 0) out[row] = sigm(v + head_b2[0]);
}

extern "C" void kernel_launch(void* const* d_in, const int* in_sizes, int n_in,
                              void* d_out, int out_size, void* d_ws, size_t ws_size,
                              hipStream_t stream) {
    (void)in_sizes; (void)n_in; (void)out_size; (void)ws_size;
    const float* x        = (const float*)d_in[0];
    const float* high_Wih = (const float*)d_in[1];
    const float* high_Whh = (const float*)d_in[2];
    const float* high_bih = (const float*)d_in[3];
    const float* high_bhh = (const float*)d_in[4];
    const float* low_Wih  = (const float*)d_in[5];
    const float* low_Whh  = (const float*)d_in[6];
    const float* low_bih  = (const float*)d_in[7];
    const float* low_bhh  = (const float*)d_in[8];
    const float* head_W1  = (const float*)d_in[9];
    const float* head_b1  = (const float*)d_in[10];
    const float* head_W2  = (const float*)d_in[11];
    const float* head_b2  = (const float*)d_in[12];
    float* ws  = (float*)d_ws;
    float* out = (float*)d_out;

    prep_weights<<<144, 256, 0, stream>>>(high_Wih, high_Whh, low_Wih, low_Whh, ws);
    hrm_main<<<256, 256, 0, stream>>>(x, high_bih, high_bhh, low_bih, low_bhh,
                                      head_W1, head_b1, head_W2, head_b2, ws, out);
}

// Round 4
// 988.530 us; speedup vs baseline: 3.7749x; 3.7749x over previous
//
#include <hip/hip_runtime.h>
#include <hip/hip_bf16.h>

// HRMHead via bf16 MFMA. B=1024, T=512, F=128, H=64, HIGH_PERIOD=10.
// Block = 4 batch rows (M=16 tile, rows 4..15 duplicate rows 0..3), 4 waves.
// Wave w owns gate-cols j = w*16..w*16+15 for all 3 gates (N-tiles {w,4+w,8+w}).
// Low weights live in VGPRs as packed B-frags; h_low/h_high in regs + tiny LDS.

#define T_STEPS 512
#define F_IN 128

typedef __attribute__((ext_vector_type(8))) short s16x8;
typedef __attribute__((ext_vector_type(4))) float f32x4;

__device__ __forceinline__ float sigm(float v) { return 1.0f / (1.0f + __expf(-v)); }
__device__ __forceinline__ float tanh_fast(float v) { return 1.0f - 2.0f / (__expf(2.0f * v) + 1.0f); }
__device__ __forceinline__ short f2b(float f) {
    __hip_bfloat16 h = __float2bfloat16(f);
    union { __hip_bfloat16 h; short s; } u; u.h = h; return u.s;
}

// ws layout (shorts): lowGi [12][6][64][8] @0 ; lowGh [12][2][64][8] @36864 ;
// highGi [12][4][64][8] @49152 ; highGh [12][2][64][8] @73728 ; W1t fp32 [64][64] @86016
__global__ void prep_pack(const float* __restrict__ hWih, const float* __restrict__ hWhh,
                          const float* __restrict__ lWih, const float* __restrict__ lWhh,
                          const float* __restrict__ headW1,
                          short* __restrict__ wsS) {
    int i = blockIdx.x * blockDim.x + threadIdx.x;
    if (i < 36864) {
        int j = i & 7, l = (i >> 3) & 63, tile = i >> 9;
        int kt = tile % 6, nt = tile / 6;
        int n = nt * 16 + (l & 15), k = kt * 32 + (l >> 4) * 8 + j;
        wsS[i] = f2b(lWih[n * 192 + k]);
    } else if (i < 49152) {
        int fi = i - 36864;
        int j = fi & 7, l = (fi >> 3) & 63, tile = fi >> 9;
        int kt = tile & 1, nt = tile >> 1;
        int n = nt * 16 + (l & 15), k = kt * 32 + (l >> 4) * 8 + j;
        wsS[i] = f2b(lWhh[n * 64 + k]);
    } else if (i < 73728) {
        int fi = i - 49152;
        int j = fi & 7, l = (fi >> 3) & 63, tile = fi >> 9;
        int kt = tile & 3, nt = tile >> 2;
        int n = nt * 16 + (l & 15), k = kt * 32 + (l >> 4) * 8 + j;
        wsS[i] = f2b(hWih[n * 128 + k]);
    } else if (i < 86016) {
        int fi = i - 73728;
        int j = fi & 7, l = (fi >> 3) & 63, tile = fi >> 9;
        int kt = tile & 1, nt = tile >> 1;
        int n = nt * 16 + (l & 15), k = kt * 32 + (l >> 4) * 8 + j;
        wsS[i] = f2b(hWhh[n * 64 + k]);
    } else if (i < 86016 + 4096) {
        int fi = i - 86016;
        int jj = fi & 63, k = fi >> 6;
        float* W1t = (float*)(wsS + 86016);
        W1t[k * 64 + jj] = headW1[jj * 64 + k];
    }
}

__global__ __launch_bounds__(256, 1)
void hrm_mfma(const float* __restrict__ x,
              const float* __restrict__ high_bih, const float* __restrict__ high_bhh,
              const float* __restrict__ low_bih,  const float* __restrict__ low_bhh,
              const float* __restrict__ head_b1,  const float* __restrict__ head_W2,
              const float* __restrict__ head_b2,
              const short* __restrict__ wsS,
              float* __restrict__ out) {
    const int tid = threadIdx.x;
    const int w = tid >> 6, l = tid & 63;
    const int lo4 = l & 15, hi4 = l >> 4;
    const int j = w * 16 + lo4;   // this lane's hidden col in elementwise phase

    const s16x8* pLGi = (const s16x8*)wsS;
    const s16x8* pLGh = (const s16x8*)(wsS + 36864);
    const s16x8* pHGi = (const s16x8*)(wsS + 49152);
    const s16x8* pHGh = (const s16x8*)(wsS + 73728);
    const float* W1t  = (const float*)(wsS + 86016);

    __shared__ __align__(16) short Ahl[2][16 * 72];  // h_low bf16 A-frags, double-buffered
    __shared__ __align__(16) short Ahh[16 * 72];     // h_high bf16 A-frags
    __shared__ float hlf[16][68];

    for (int i = tid; i < 2 * 16 * 72; i += 256) ((short*)Ahl)[i] = 0;
    for (int i = tid; i < 16 * 72; i += 256) Ahh[i] = 0;

    float lbi[3], lbh[3], hbi[3], hbh[3];
    #pragma unroll
    for (int g = 0; g < 3; ++g) {
        lbi[g] = low_bih[g * 64 + j];  lbh[g] = low_bhh[g * 64 + j];
        hbi[g] = high_bih[g * 64 + j]; hbh[g] = high_bhh[g * 64 + j];
    }

    // low-cell weights resident in VGPRs (one-time load, L2-broadcast)
    s16x8 Bgi[3][6], Bgh[3][2];
    #pragma unroll
    for (int g = 0; g < 3; ++g) {
        #pragma unroll
        for (int kt = 0; kt < 6; ++kt) Bgi[g][kt] = pLGi[((g * 4 + w) * 6 + kt) * 64 + l];
        #pragma unroll
        for (int kt = 0; kt < 2; ++kt) Bgh[g][kt] = pLGh[((g * 4 + w) * 2 + kt) * 64 + l];
    }

    float hl[4] = {0.f, 0.f, 0.f, 0.f};
    float hh[4] = {0.f, 0.f, 0.f, 0.f};

    const int r0 = blockIdx.x * 4;
    // A-frag row (lo4) -> real row (lo4 & 3); lane reads 8 consecutive floats of x
    const float* xlane = x + ((size_t)(r0 + (lo4 & 3)) * T_STEPS) * F_IN + hi4 * 8;

    f32x4 xraw[4][2];
    #pragma unroll
    for (int kt = 0; kt < 4; ++kt) {
        xraw[kt][0] = *(const f32x4*)(xlane + kt * 32);
        xraw[kt][1] = *(const f32x4*)(xlane + kt * 32 + 4);
    }

    __syncthreads();

    int tmod = 0;
    for (int t = 0; t < T_STEPS; ++t) {
        // convert current x to bf16 A-frags
        s16x8 xf[4];
        #pragma unroll
        for (int kt = 0; kt < 4; ++kt) {
            union { s16x8 v; __hip_bfloat162 h2[4]; } u;
            u.h2[0] = __float22bfloat162_rn(make_float2(xraw[kt][0].x, xraw[kt][0].y));
            u.h2[1] = __float22bfloat162_rn(make_float2(xraw[kt][0].z, xraw[kt][0].w));
            u.h2[2] = __float22bfloat162_rn(make_float2(xraw[kt][1].x, xraw[kt][1].y));
            u.h2[3] = __float22bfloat162_rn(make_float2(xraw[kt][1].z, xraw[kt][1].w));
            xf[kt] = u.v;
        }

        const int rb = t & 1, wbf = rb ^ 1;

        if (tmod == 0) {
            // ---- high GRU cell (uses OLD h_high, x_t) ----
            s16x8 ah0 = *(const s16x8*)&Ahh[lo4 * 72 + hi4 * 8];
            s16x8 ah1 = *(const s16x8*)&Ahh[lo4 * 72 + 32 + hi4 * 8];
            f32x4 gi[3], gh[3];
            #pragma unroll
            for (int g = 0; g < 3; ++g) {
                gi[g] = (f32x4){hbi[g], hbi[g], hbi[g], hbi[g]};
                gh[g] = (f32x4){hbh[g], hbh[g], hbh[g], hbh[g]};
            }
            #pragma unroll
            for (int g = 0; g < 3; ++g) {
                s16x8 b0 = pHGh[((g * 4 + w) * 2 + 0) * 64 + l];
                s16x8 b1 = pHGh[((g * 4 + w) * 2 + 1) * 64 + l];
                gh[g] = __builtin_amdgcn_mfma_f32_16x16x32_bf16(ah0, b0, gh[g], 0, 0, 0);
                gh[g] = __builtin_amdgcn_mfma_f32_16x16x32_bf16(ah1, b1, gh[g], 0, 0, 0);
            }
            #pragma unroll
            for (int g = 0; g < 3; ++g) {
                #pragma unroll
                for (int kt = 0; kt < 4; ++kt) {
                    s16x8 b = pHGi[((g * 4 + w) * 4 + kt) * 64 + l];
                    gi[g] = __builtin_amdgcn_mfma_f32_16x16x32_bf16(xf[kt], b, gi[g], 0, 0, 0);
                }
            }
            #pragma unroll
            for (int q = 0; q < 4; ++q) {
                float r = sigm(gi[0][q] + gh[0][q]);
                float z = sigm(gi[1][q] + gh[1][q]);
                float n = tanh_fast(gi[2][q] + r * gh[2][q]);
                hh[q] = (1.0f - z) * n + z * hh[q];
            }
            __syncthreads();   // all waves done reading old Ahh
            #pragma unroll
            for (int q = 0; q < 4; ++q)
                Ahh[(hi4 * 4 + q) * 72 + j] = f2b(hh[q]);
            __syncthreads();   // new Ahh visible
        }
        if (++tmod == 10) tmod = 0;

        // ---- low GRU cell ----
        s16x8 al0 = *(const s16x8*)&Ahl[rb][lo4 * 72 + hi4 * 8];
        s16x8 al1 = *(const s16x8*)&Ahl[rb][lo4 * 72 + 32 + hi4 * 8];
        s16x8 ah0 = *(const s16x8*)&Ahh[lo4 * 72 + hi4 * 8];
        s16x8 ah1 = *(const s16x8*)&Ahh[lo4 * 72 + 32 + hi4 * 8];

        f32x4 gi[3], gh[3];
        #pragma unroll
        for (int g = 0; g < 3; ++g) {
            gi[g] = (f32x4){lbi[g], lbi[g], lbi[g], lbi[g]};
            gh[g] = (f32x4){lbh[g], lbh[g], lbh[g], lbh[g]};
        }
        #pragma unroll
        for (int g = 0; g < 3; ++g) {
            gh[g] = __builtin_amdgcn_mfma_f32_16x16x32_bf16(al0, Bgh[g][0], gh[g], 0, 0, 0);
            gh[g] = __builtin_amdgcn_mfma_f32_16x16x32_bf16(al1, Bgh[g][1], gh[g], 0, 0, 0);
        }
        #pragma unroll
        for (int g = 0; g < 3; ++g) {
            #pragma unroll
            for (int kt = 0; kt < 4; ++kt)
                gi[g] = __builtin_amdgcn_mfma_f32_16x16x32_bf16(xf[kt], Bgi[g][kt], gi[g], 0, 0, 0);
            gi[g] = __builtin_amdgcn_mfma_f32_16x16x32_bf16(ah0, Bgi[g][4], gi[g], 0, 0, 0);
            gi[g] = __builtin_amdgcn_mfma_f32_16x16x32_bf16(ah1, Bgi[g][5], gi[g], 0, 0, 0);
        }

        // prefetch x for t+1 (hides HBM latency under elementwise + barrier)
        if (t + 1 < T_STEPS) {
            #pragma unroll
            for (int kt = 0; kt < 4; ++kt) {
                xraw[kt][0] = *(const f32x4*)(xlane + (size_t)(t + 1) * F_IN + kt * 32);
                xraw[kt][1] = *(const f32x4*)(xlane + (size_t)(t + 1) * F_IN + kt * 32 + 4);
            }
        }

        #pragma unroll
        for (int q = 0; q < 4; ++q) {
            float r = sigm(gi[0][q] + gh[0][q]);
            float z = sigm(gi[1][q] + gh[1][q]);
            float n = tanh_fast(gi[2][q] + r * gh[2][q]);
            hl[q] = (1.0f - z) * n + z * hl[q];
        }
        #pragma unroll
        for (int q = 0; q < 4; ++q)
            Ahl[wbf][(hi4 * 4 + q) * 72 + j] = f2b(hl[q]);
        __syncthreads();   // Ahl[wbf] visible for next step
    }

    // ---- head ----
    #pragma unroll
    for (int q = 0; q < 4; ++q) hlf[hi4 * 4 + q][j] = hl[q];
    __syncthreads();

    // wave w handles real row w (rows 0..3); lane l = hidden unit
    float hd = head_b1[l];
    for (int k = 0; k < 64; ++k)
        hd = fmaf(hlf[w][k], W1t[k * 64 + l], hd);
    hd = fmaxf(hd, 0.0f);
    float v = hd * head_W2[l];
    #pragma unroll
    for (int off = 32; off > 0; off >>= 1) v += __shfl_down(v, off);
    if (l == 0) out[r0 + w] = sigm(v + head_b2[0]);
}

extern "C" void kernel_launch(void* const* d_in, const int* in_sizes, int n_in,
                              void* d_out, int out_size, void* d_ws, size_t ws_size,
                              hipStream_t stream) {
    (void)in_sizes; (void)n_in; (void)out_size; (void)ws_size;
    const float* x        = (const float*)d_in[0];
    const float* high_Wih = (const float*)d_in[1];
    const float* high_Whh = (const float*)d_in[2];
    const float* high_bih = (const float*)d_in[3];
    const float* high_bhh = (const float*)d_in[4];
    const float* low_Wih  = (const float*)d_in[5];
    const float* low_Whh  = (const float*)d_in[6];
    const float* low_bih  = (const float*)d_in[7];
    const float* low_bhh  = (const float*)d_in[8];
    const float* head_W1  = (const float*)d_in[9];
    const float* head_b1  = (const float*)d_in[10];
    const float* head_W2  = (const float*)d_in[11];
    const float* head_b2  = (const float*)d_in[12];
    short* wsS = (short*)d_ws;
    float* out = (float*)d_out;

    prep_pack<<<352, 256, 0, stream>>>(high_Wih, high_Whh, low_Wih, low_Whh, head_W1, wsS);
    hrm_mfma<<<256, 256, 0, stream>>>(x, high_bih, high_bhh, low_bih, low_bhh,
                                      head_b1, head_W2, head_b2, wsS, out);
}